// Round 6
// baseline (8550.457 us; speedup 1.0000x reference)
//
#include <hip/hip_runtime.h>
#include <cstdio>
#include <cstdint>

#define TT 1024
#define DD 1024
#define HH 1024
#define NN 32
#define G4 4096

using bf16x8   = __attribute__((ext_vector_type(8))) __bf16;
using f32x4    = __attribute__((ext_vector_type(4))) float;
using uint32x4 = __attribute__((ext_vector_type(4))) unsigned int;

typedef const __attribute__((address_space(1))) void* gas_cp;
typedef __attribute__((address_space(3))) void* las_p;

__device__ __forceinline__ unsigned short f2bf(float f) {
  unsigned int u = __builtin_bit_cast(unsigned int, f);
  u = u + 0x7fffu + ((u >> 16) & 1u);
  return (unsigned short)(u >> 16);
}
__device__ __forceinline__ float bf2f(unsigned short s) {
  unsigned int u = ((unsigned int)s) << 16;
  return __builtin_bit_cast(float, u);
}
__device__ __forceinline__ float sigm(float x) { return 1.f / (1.f + __expf(-x)); }
__device__ __forceinline__ float tanh_f(float x) {
  float a = fabsf(x);
  float e = __expf(-2.f * a);
  float r = (1.f - e) / (1.f + e);
  return x < 0.f ? -r : r;
}

// ---- cast x (f32 -> bf16)
__global__ void cast_bf4(const float4* __restrict__ in, uint2* __restrict__ o, int n4) {
  int i = blockIdx.x * 256 + threadIdx.x;
  if (i < n4) {
    float4 v = in[i];
    uint2 r;
    r.x = (unsigned int)f2bf(v.x) | ((unsigned int)f2bf(v.y) << 16);
    r.y = (unsigned int)f2bf(v.z) | ((unsigned int)f2bf(v.w) << 16);
    o[i] = r;
  }
}

// ---- transpose+cast: in [R][C] f32 -> out [C][R] bf16
__global__ void transp_cast(const float* __restrict__ in, unsigned short* __restrict__ outT,
                            int R, int C) {
  __shared__ unsigned short t[64][65];
  int nbc = C >> 6;
  int tc = blockIdx.x % nbc, tr = blockIdx.x / nbc;
  int r0 = tr << 6, c0 = tc << 6;
  for (int i = threadIdx.x; i < 4096; i += 256) {
    int r = i >> 6, c = i & 63;
    t[c][r] = f2bf(in[(size_t)(r0 + r) * C + c0 + c]);
  }
  __syncthreads();
  for (int i = threadIdx.x; i < 4096; i += 256) {
    int c = i >> 6, r = i & 63;
    outT[(size_t)(c0 + c) * R + r0 + r] = t[c][r];
  }
}

// ---- pack h0 into tagged u32 buffer (tag = 0); layout [cl][r][1024] == [n][1024]
__global__ void pack_h0(const float* __restrict__ in, unsigned int* __restrict__ o) {
  int i = blockIdx.x * 256 + threadIdx.x;
  o[i] = (unsigned int)f2bf(in[i]);
}

// ---- Phase 1: xw packed as [t][cl][jw][r][jc][g] bf16 (u64 of 4 gates per cell)
#define BM 128
#define BN 128
#define BK 64

__launch_bounds__(256, 2)
__global__ void gemm_xw(const unsigned short* __restrict__ A,   // [32768][1024] bf16 (m = n*T+t)
                        const unsigned short* __restrict__ B,   // [4096][1024] bf16 (WxT)
                        const float* __restrict__ bias,         // [4096]
                        unsigned short* __restrict__ C)         // [1024][8][32][4][32][4] bf16
{
  __shared__ alignas(16) unsigned short As[BM * BK];
  __shared__ alignas(16) unsigned short Bs[BN * BK];
  int bid = blockIdx.x;
  int swz = (bid & 7) * 1024 + (bid >> 3);
  int grp = swz >> 8;
  int loc = swz & 255;
  int tm = (grp << 3) + (loc & 7);
  int tn = loc >> 3;
  int tid = threadIdx.x;
  int w = tid >> 6, lane = tid & 63;
  int wr = w >> 1, wc = w & 1;

  f32x4 acc[4][4] = {};

  const size_t rowA0 = (size_t)tm * BM;
  const size_t colB0 = (size_t)tn * BN;

  for (int k0 = 0; k0 < DD; k0 += BK) {
    #pragma unroll
    for (int i = 0; i < 4; ++i) {
      int chunk = w * 4 + i;
      int p = chunk * 1024 + lane * 16;
      int row = p >> 7;
      int bo = p & 127;
      int gb = bo ^ ((row & 7) << 4);
      const char* ga = (const char*)(A + (rowA0 + row) * DD + k0) + gb;
      __builtin_amdgcn_global_load_lds((gas_cp)ga, (las_p)((char*)As + chunk * 1024), 16, 0, 0);
      const char* gB = (const char*)(B + (colB0 + row) * DD + k0) + gb;
      __builtin_amdgcn_global_load_lds((gas_cp)gB, (las_p)((char*)Bs + chunk * 1024), 16, 0, 0);
    }
    __syncthreads();

    #pragma unroll
    for (int ks = 0; ks < 2; ++ks) {
      bf16x8 af[4], bfr[4];
      #pragma unroll
      for (int mi = 0; mi < 4; ++mi) {
        int row = wr * 64 + mi * 16 + (lane & 15);
        int kb = (ks * 32 + ((lane >> 4) << 3)) * 2;
        af[mi] = *(const bf16x8*)((const char*)As + row * 128 + (kb ^ ((row & 7) << 4)));
      }
      #pragma unroll
      for (int ni = 0; ni < 4; ++ni) {
        int row = wc * 64 + ni * 16 + (lane & 15);
        int kb = (ks * 32 + ((lane >> 4) << 3)) * 2;
        bfr[ni] = *(const bf16x8*)((const char*)Bs + row * 128 + (kb ^ ((row & 7) << 4)));
      }
      #pragma unroll
      for (int mi = 0; mi < 4; ++mi)
        #pragma unroll
        for (int ni = 0; ni < 4; ++ni)
          acc[mi][ni] = __builtin_amdgcn_mfma_f32_16x16x32_bf16(af[mi], bfr[ni], acc[mi][ni], 0, 0, 0);
    }
    __syncthreads();
  }

  #pragma unroll
  for (int ni = 0; ni < 4; ++ni) {
    int col = (int)colB0 + wc * 64 + ni * 16 + (lane & 15);
    float bb = bias[col];
    int g = col >> 10, J = col & 1023;
    int jw2 = J >> 5, jc2 = J & 31;
    #pragma unroll
    for (int mi = 0; mi < 4; ++mi) {
      #pragma unroll
      for (int r = 0; r < 4; ++r) {
        size_t row = rowA0 + wr * 64 + mi * 16 + ((lane >> 4) << 2) + r;  // m = n*T + t
        size_t n2 = row >> 10, t2 = row & 1023;
        size_t cl = n2 >> 2, rr = n2 & 3;
        C[((((t2 * 8 + cl) * 32 + jw2) * 4 + rr) * 32 + jc2) * 4 + g] = f2bf(acc[mi][ni][r] + bb);
      }
    }
  }
}

// ---- Phase 2: 8 XCD-local clusters x 4 samples, 256 wgs x 512 threads.
// Wh slice pinned in registers via asm loads. Per-wg step flags (hint) gate a
// single tag-verified A-burst (ground truth). Only lanes (lane&15)<4 load A.
#define LDA0(dst, off) asm volatile("global_load_dwordx2 %0, %1, off offset:" #off " sc0" : "=v"(dst) : "v"(hq))
#define LDA1(dst, off) asm volatile("global_load_dwordx2 %0, %1, off offset:" #off " sc0 sc1" : "=v"(dst) : "v"(hq))
#define LDW(dst, addr, off) asm volatile("global_load_dwordx4 %0, %1, off offset:" #off : "=v"(dst) : "v"(addr))

__launch_bounds__(512, 2)
__global__ void lstm_rec(const unsigned long long* __restrict__ xw,  // [1024][8][32][128] u64
                         const unsigned short* __restrict__ WhT,     // [4096][1024] bf16
                         unsigned int* __restrict__ hbuf,            // [2][8][4][1024] u32 tagged
                         unsigned int* __restrict__ flags,           // [8][32]
                         float* __restrict__ out)                    // [32][1024][1024] f32
{
  __shared__ float red[2][8][4][128];   // [par][kq][sample][gatecol] : 32 KB

  const int bid = blockIdx.x;
  const int cl = bid & 7;          // cluster (XCD via round-robin, perf-only)
  const int jw = bid >> 3;         // wg-in-cluster: h-cols jw*32..+32
  const int j0 = jw * 32;
  const int tid = threadIdx.x;
  const int lane = tid & 63;
  const int kq = tid >> 6;         // wave = K-eighth (128 k)
  const int l15 = lane & 15;
  const int q4 = lane >> 4;

  // ---- Wh slice -> registers via asm (non-rematerializable), once.
  // lane holds gatecol cc = tile*16+l15 -> (cc>>5)*1024 + j0 + (cc&31); k = kq*128+ks*32+q4*8
  bf16x8 Bf[8][4];
  #pragma unroll
  for (int tile = 0; tile < 8; ++tile) {
    int cc = tile * 16 + l15;
    int gcol = (cc >> 5) * 1024 + j0 + (cc & 31);
    const unsigned short* wb = WhT + (size_t)gcol * HH + kq * 128 + q4 * 8;
    LDW(Bf[tile][0], wb, 0);
    LDW(Bf[tile][1], wb, 64);
    LDW(Bf[tile][2], wb, 128);
    LDW(Bf[tile][3], wb, 192);
  }
  asm volatile("s_waitcnt vmcnt(0)");

  const bool ld = (l15 < 4);       // only 16 lanes carry real A rows
  const int r4row = lane & 3;
  const int er = tid >> 5, ej = tid & 31;   // epilogue cell (tid<128)
  float c = 0.f;
  const unsigned long long M64 = 0xFFFF0000FFFF0000ULL;

  unsigned long long u0=0,u1=0,u2=0,u3=0,u4=0,u5=0,u6=0,u7=0,
                     u8=0,u9=0,u10=0,u11=0,u12=0,u13=0,u14=0,u15=0;

  // prime xw prefetch for t=0
  unsigned long long xq = 0;
  if (tid < 128) xq = xw[(((size_t)0 * 8 + cl) * 32 + jw) * 128 + tid];

  #pragma unroll 1
  for (int t = 0; t < TT; ++t) {
    const int par = t & 1;
    const unsigned int* hc = hbuf + (size_t)par * 32768 + cl * 4096;
    unsigned int* hn = hbuf + (size_t)(par ^ 1) * 32768 + cl * 4096;

    // ---- flag poll (hint): 4 producer wgs of this wave's K-slice, uniform
    {
      const unsigned int* fp = flags + cl * 32 + kq * 4;
      uint32x4 fv;
      int rc = 0;
      for (;;) {
        if (!(rc & 1)) asm volatile("global_load_dwordx4 %0, %1, off sc0" : "=v"(fv) : "v"(fp));
        else           asm volatile("global_load_dwordx4 %0, %1, off sc0 sc1" : "=v"(fv) : "v"(fp));
        asm volatile("s_waitcnt vmcnt(0)");
        if (fv[0] >= (unsigned)t && fv[1] >= (unsigned)t &&
            fv[2] >= (unsigned)t && fv[3] >= (unsigned)t) break;
        __builtin_amdgcn_s_sleep(1);
        ++rc;
      }
    }

    // ---- one-shot A-burst, tag-verified (ground truth; retries rare)
    const unsigned long long pat =
        ((unsigned long long)(unsigned)t << 16) | ((unsigned long long)(unsigned)t << 48);
    if (ld) {
      const unsigned long long* hq =
          (const unsigned long long*)(hc + r4row * 1024 + kq * 128 + q4 * 8);
      int rc = 0;
      for (;;) {
        if (!(rc & 1)) {
          LDA0(u0,0);   LDA0(u1,8);   LDA0(u2,16);  LDA0(u3,24);
          LDA0(u4,128); LDA0(u5,136); LDA0(u6,144); LDA0(u7,152);
          LDA0(u8,256); LDA0(u9,264); LDA0(u10,272);LDA0(u11,280);
          LDA0(u12,384);LDA0(u13,392);LDA0(u14,400);LDA0(u15,408);
        } else {
          LDA1(u0,0);   LDA1(u1,8);   LDA1(u2,16);  LDA1(u3,24);
          LDA1(u4,128); LDA1(u5,136); LDA1(u6,144); LDA1(u7,152);
          LDA1(u8,256); LDA1(u9,264); LDA1(u10,272);LDA1(u11,280);
          LDA1(u12,384);LDA1(u13,392);LDA1(u14,400);LDA1(u15,408);
        }
        asm volatile("s_waitcnt vmcnt(0)");
        __builtin_amdgcn_sched_barrier(0);
        unsigned long long bad =
            ((u0 & M64) ^ pat)  | ((u1 & M64) ^ pat)  | ((u2 & M64) ^ pat)  | ((u3 & M64) ^ pat)  |
            ((u4 & M64) ^ pat)  | ((u5 & M64) ^ pat)  | ((u6 & M64) ^ pat)  | ((u7 & M64) ^ pat)  |
            ((u8 & M64) ^ pat)  | ((u9 & M64) ^ pat)  | ((u10 & M64) ^ pat) | ((u11 & M64) ^ pat) |
            ((u12 & M64) ^ pat) | ((u13 & M64) ^ pat) | ((u14 & M64) ^ pat) | ((u15 & M64) ^ pat);
        if (!__any(bad != 0)) break;
        __builtin_amdgcn_s_sleep(1);
        ++rc;
      }
    }

    // ---- prefetch NEXT step's xw under the MFMA phase
    unsigned long long xq_n = 0;
    if (tid < 128) {
      int tp = (t + 1 < TT) ? t + 1 : 0;
      xq_n = xw[(((size_t)tp * 8 + cl) * 32 + jw) * 128 + tid];
    }

    // ---- unpack tags out (v_perm) and MFMA: 8 tiles x 4 k-steps
    f32x4 acc[8] = {};
    {
      uint32x4 wv;
      #define KSTEP(ks, a0, a1, a2, a3)                                              \
        wv[0] = __builtin_amdgcn_perm((unsigned)((a0) >> 32), (unsigned)(a0), 0x05040100u); \
        wv[1] = __builtin_amdgcn_perm((unsigned)((a1) >> 32), (unsigned)(a1), 0x05040100u); \
        wv[2] = __builtin_amdgcn_perm((unsigned)((a2) >> 32), (unsigned)(a2), 0x05040100u); \
        wv[3] = __builtin_amdgcn_perm((unsigned)((a3) >> 32), (unsigned)(a3), 0x05040100u); \
        { bf16x8 av = __builtin_bit_cast(bf16x8, wv);                                \
          _Pragma("unroll")                                                          \
          for (int tile = 0; tile < 8; ++tile)                                       \
            acc[tile] = __builtin_amdgcn_mfma_f32_16x16x32_bf16(av, Bf[tile][ks], acc[tile], 0, 0, 0); }
      KSTEP(0, u0, u1, u2, u3)
      KSTEP(1, u4, u5, u6, u7)
      KSTEP(2, u8, u9, u10, u11)
      KSTEP(3, u12, u13, u14, u15)
      #undef KSTEP
    }

    if (q4 == 0) {
      #pragma unroll
      for (int tile = 0; tile < 8; ++tile)
        #pragma unroll
        for (int rg = 0; rg < 4; ++rg)
          red[par][kq][rg][tile * 16 + l15] = acc[tile][rg];
    }
    __syncthreads();

    // ---- epilogue: thread (er, ej) owns sample er, h-col j0+ej
    if (tid < 128) {
      float s0 = 0.f, s1 = 0.f, s2 = 0.f, s3 = 0.f;
      #pragma unroll
      for (int k2 = 0; k2 < 8; ++k2) {
        s0 += red[par][k2][er][ej];
        s1 += red[par][k2][er][32 + ej];
        s2 += red[par][k2][er][64 + ej];
        s3 += red[par][k2][er][96 + ej];
      }
      float ai  = s0 + bf2f((unsigned short)xq);
      float af_ = s1 + bf2f((unsigned short)(xq >> 16));
      float ao  = s2 + bf2f((unsigned short)(xq >> 32));
      float ag  = s3 + bf2f((unsigned short)(xq >> 48));
      float ig = sigm(ai), fg = sigm(af_), og = sigm(ao);
      float gg = tanh_f(ag);
      c = fg * c + ig * gg;
      float hv = og * tanh_f(c);

      unsigned int hp = (unsigned int)f2bf(hv) | ((unsigned int)(t + 1) << 16);
      __hip_atomic_store(hn + er * 1024 + j0 + ej, hp,
                         __ATOMIC_RELAXED, __HIP_MEMORY_SCOPE_AGENT);
      if (tid == 0) {
        asm volatile("s_waitcnt vmcnt(0)");   // wave0's h stores at coherence point
        __hip_atomic_store(&flags[cl * 32 + jw], (unsigned)(t + 1),
                           __ATOMIC_RELAXED, __HIP_MEMORY_SCOPE_AGENT);
      }
      out[((size_t)(cl * 4 + er) * TT + t) * HH + j0 + ej] = hv;
    }
    xq = xq_n;
  }
}

extern "C" void kernel_launch(void* const* d_in, const int* in_sizes, int n_in,
                              void* d_out, int out_size, void* d_ws, size_t ws_size,
                              hipStream_t stream) {
  (void)in_sizes; (void)n_in; (void)out_size;
  const float* x  = (const float*)d_in[0];
  const float* h0 = (const float*)d_in[1];
  const float* Wx = (const float*)d_in[2];
  const float* Wh = (const float*)d_in[3];
  const float* b  = (const float*)d_in[4];
  float* out = (float*)d_out;

  char* ws = (char*)d_ws;
  size_t o_xw  = 0;
  size_t o_xbf = o_xw  + (size_t)32768 * 4096 * 2;  // xw   : 268435456 B
  size_t o_wxT = o_xbf + (size_t)32768 * 1024 * 2;  // xbf  :  67108864 B
  size_t o_whT = o_wxT + (size_t)4096 * 1024 * 2;   // WxT  :   8388608 B
  size_t o_hb  = o_whT + (size_t)4096 * 1024 * 2;   // WhT  :   8388608 B
  size_t o_fl  = o_hb  + (size_t)2 * 32768 * 4;     // hbuf :    262144 B
  size_t need  = o_fl + 4096;                       // flags
  if (ws_size < need) {
    fprintf(stderr, "kernel_launch: ws_size %zu < needed %zu\n", ws_size, need);
    return;
  }
  unsigned short* xw  = (unsigned short*)(ws + o_xw);
  unsigned short* xbf = (unsigned short*)(ws + o_xbf);
  unsigned short* wxT = (unsigned short*)(ws + o_wxT);
  unsigned short* whT = (unsigned short*)(ws + o_whT);
  unsigned int*   hb  = (unsigned int*)(ws + o_hb);
  unsigned int*   fl  = (unsigned int*)(ws + o_fl);

  // re-init all cross-replay state: stale tags killed, flags zeroed, h0 tag 0
  hipMemsetAsync(hb, 0xFF, (size_t)2 * 32768 * 4, stream);
  hipMemsetAsync(fl, 0, 4096, stream);
  pack_h0<<<128, 256, 0, stream>>>(h0, hb);
  cast_bf4<<<32768, 256, 0, stream>>>((const float4*)x, (uint2*)xbf, 33554432 / 4);
  transp_cast<<<1024, 256, 0, stream>>>(Wx, wxT, 1024, 4096);
  transp_cast<<<1024, 256, 0, stream>>>(Wh, whT, 1024, 4096);
  gemm_xw<<<8192, 256, 0, stream>>>(xbf, wxT, b, xw);

  void* args[] = { (void*)&xw, (void*)&whT, (void*)&hb, (void*)&fl, (void*)&out };
  hipLaunchCooperativeKernel(lstm_rec, dim3(256), dim3(512), args, 0, stream);
}

// Round 7
// 4489.912 us; speedup vs baseline: 1.9044x; 1.9044x over previous
//
#include <hip/hip_runtime.h>
#include <cstdio>
#include <cstdint>

#define TT 1024
#define DD 1024
#define HH 1024
#define NN 32
#define G4 4096

using bf16x8   = __attribute__((ext_vector_type(8))) __bf16;
using f32x4    = __attribute__((ext_vector_type(4))) float;
using uint32x4 = __attribute__((ext_vector_type(4))) unsigned int;

typedef const __attribute__((address_space(1))) void* gas_cp;
typedef __attribute__((address_space(3))) void* las_p;

__device__ __forceinline__ unsigned short f2bf(float f) {
  unsigned int u = __builtin_bit_cast(unsigned int, f);
  u = u + 0x7fffu + ((u >> 16) & 1u);
  return (unsigned short)(u >> 16);
}
__device__ __forceinline__ float bf2f(unsigned short s) {
  unsigned int u = ((unsigned int)s) << 16;
  return __builtin_bit_cast(float, u);
}
__device__ __forceinline__ float sigm(float x) { return 1.f / (1.f + __expf(-x)); }
__device__ __forceinline__ float tanh_f(float x) {
  float a = fabsf(x);
  float e = __expf(-2.f * a);
  float r = (1.f - e) / (1.f + e);
  return x < 0.f ? -r : r;
}

// ---- cast x (f32 -> bf16)
__global__ void cast_bf4(const float4* __restrict__ in, uint2* __restrict__ o, int n4) {
  int i = blockIdx.x * 256 + threadIdx.x;
  if (i < n4) {
    float4 v = in[i];
    uint2 r;
    r.x = (unsigned int)f2bf(v.x) | ((unsigned int)f2bf(v.y) << 16);
    r.y = (unsigned int)f2bf(v.z) | ((unsigned int)f2bf(v.w) << 16);
    o[i] = r;
  }
}

// ---- transpose+cast: in [R][C] f32 -> out [C][R] bf16
__global__ void transp_cast(const float* __restrict__ in, unsigned short* __restrict__ outT,
                            int R, int C) {
  __shared__ unsigned short t[64][65];
  int nbc = C >> 6;
  int tc = blockIdx.x % nbc, tr = blockIdx.x / nbc;
  int r0 = tr << 6, c0 = tc << 6;
  for (int i = threadIdx.x; i < 4096; i += 256) {
    int r = i >> 6, c = i & 63;
    t[c][r] = f2bf(in[(size_t)(r0 + r) * C + c0 + c]);
  }
  __syncthreads();
  for (int i = threadIdx.x; i < 4096; i += 256) {
    int c = i >> 6, r = i & 63;
    outT[(size_t)(c0 + c) * R + r0 + r] = t[c][r];
  }
}

// ---- pack h0 into tagged u32 buffer (tag = 0); layout [cl][r][1024] == [n][1024]
__global__ void pack_h0(const float* __restrict__ in, unsigned int* __restrict__ o) {
  int i = blockIdx.x * 256 + threadIdx.x;
  o[i] = (unsigned int)f2bf(in[i]);
}

// ---- Phase 1: xw packed as [t][cl][jw][r][jc][g] bf16 (u64 of 4 gates per cell)
#define BM 128
#define BN 128
#define BK 64

__launch_bounds__(256, 2)
__global__ void gemm_xw(const unsigned short* __restrict__ A,   // [32768][1024] bf16 (m = n*T+t)
                        const unsigned short* __restrict__ B,   // [4096][1024] bf16 (WxT)
                        const float* __restrict__ bias,         // [4096]
                        unsigned short* __restrict__ C)         // [1024][8][32][4][32][4] bf16
{
  __shared__ alignas(16) unsigned short As[BM * BK];
  __shared__ alignas(16) unsigned short Bs[BN * BK];
  int bid = blockIdx.x;
  int swz = (bid & 7) * 1024 + (bid >> 3);
  int grp = swz >> 8;
  int loc = swz & 255;
  int tm = (grp << 3) + (loc & 7);
  int tn = loc >> 3;
  int tid = threadIdx.x;
  int w = tid >> 6, lane = tid & 63;
  int wr = w >> 1, wc = w & 1;

  f32x4 acc[4][4] = {};

  const size_t rowA0 = (size_t)tm * BM;
  const size_t colB0 = (size_t)tn * BN;

  for (int k0 = 0; k0 < DD; k0 += BK) {
    #pragma unroll
    for (int i = 0; i < 4; ++i) {
      int chunk = w * 4 + i;
      int p = chunk * 1024 + lane * 16;
      int row = p >> 7;
      int bo = p & 127;
      int gb = bo ^ ((row & 7) << 4);
      const char* ga = (const char*)(A + (rowA0 + row) * DD + k0) + gb;
      __builtin_amdgcn_global_load_lds((gas_cp)ga, (las_p)((char*)As + chunk * 1024), 16, 0, 0);
      const char* gB = (const char*)(B + (colB0 + row) * DD + k0) + gb;
      __builtin_amdgcn_global_load_lds((gas_cp)gB, (las_p)((char*)Bs + chunk * 1024), 16, 0, 0);
    }
    __syncthreads();

    #pragma unroll
    for (int ks = 0; ks < 2; ++ks) {
      bf16x8 af[4], bfr[4];
      #pragma unroll
      for (int mi = 0; mi < 4; ++mi) {
        int row = wr * 64 + mi * 16 + (lane & 15);
        int kb = (ks * 32 + ((lane >> 4) << 3)) * 2;
        af[mi] = *(const bf16x8*)((const char*)As + row * 128 + (kb ^ ((row & 7) << 4)));
      }
      #pragma unroll
      for (int ni = 0; ni < 4; ++ni) {
        int row = wc * 64 + ni * 16 + (lane & 15);
        int kb = (ks * 32 + ((lane >> 4) << 3)) * 2;
        bfr[ni] = *(const bf16x8*)((const char*)Bs + row * 128 + (kb ^ ((row & 7) << 4)));
      }
      #pragma unroll
      for (int mi = 0; mi < 4; ++mi)
        #pragma unroll
        for (int ni = 0; ni < 4; ++ni)
          acc[mi][ni] = __builtin_amdgcn_mfma_f32_16x16x32_bf16(af[mi], bfr[ni], acc[mi][ni], 0, 0, 0);
    }
    __syncthreads();
  }

  #pragma unroll
  for (int ni = 0; ni < 4; ++ni) {
    int col = (int)colB0 + wc * 64 + ni * 16 + (lane & 15);
    float bb = bias[col];
    int g = col >> 10, J = col & 1023;
    int jw2 = J >> 5, jc2 = J & 31;
    #pragma unroll
    for (int mi = 0; mi < 4; ++mi) {
      #pragma unroll
      for (int r = 0; r < 4; ++r) {
        size_t row = rowA0 + wr * 64 + mi * 16 + ((lane >> 4) << 2) + r;  // m = n*T + t
        size_t n2 = row >> 10, t2 = row & 1023;
        size_t cl = n2 >> 2, rr = n2 & 3;
        C[((((t2 * 8 + cl) * 32 + jw2) * 4 + rr) * 32 + jc2) * 4 + g] = f2bf(acc[mi][ni][r] + bb);
      }
    }
  }
}

// ---- Phase 2: 8 XCD-local clusters x 4 samples, 256 wgs x 512 threads.
// launch_bounds(512,1): VGPR cap 256 so the 128-VGPR Wh slice actually fits
// in registers (rounds 5/6 were silently capped at 128 by the ",2" bound).
// Sync: self-timed tagged h data (tag16|bf16), direct poll, no flags/fences.
#define LDA0(dst, off) asm volatile("global_load_dwordx2 %0, %1, off offset:" #off " sc0" : "=v"(dst) : "v"(hq))
#define LDA1(dst, off) asm volatile("global_load_dwordx2 %0, %1, off offset:" #off " sc0 sc1" : "=v"(dst) : "v"(hq))
#define LDW(dst, addr, off) asm volatile("global_load_dwordx4 %0, %1, off offset:" #off : "=v"(dst) : "v"(addr))

__launch_bounds__(512, 1)
__global__ void lstm_rec(const unsigned long long* __restrict__ xw,  // [1024][8][32][128] u64
                         const unsigned short* __restrict__ WhT,     // [4096][1024] bf16
                         unsigned int* __restrict__ hbuf,            // [2][8][4][1024] u32 tagged
                         float* __restrict__ out)                    // [32][1024][1024] f32
{
  __shared__ float red[2][8][4][128];   // [par][kq][sample][gatecol] : 32 KB

  const int bid = blockIdx.x;
  const int cl = bid & 7;          // cluster (XCD via round-robin, perf-only)
  const int jw = bid >> 3;         // wg-in-cluster: h-cols jw*32..+32
  const int j0 = jw * 32;
  const int tid = threadIdx.x;
  const int lane = tid & 63;
  const int kq = tid >> 6;         // wave = K-eighth (128 k)
  const int l15 = lane & 15;
  const int q4 = lane >> 4;

  // ---- Wh slice -> registers via asm (non-rematerializable), once.
  bf16x8 Bf[8][4];
  #pragma unroll
  for (int tile = 0; tile < 8; ++tile) {
    int cc = tile * 16 + l15;
    int gcol = (cc >> 5) * 1024 + j0 + (cc & 31);
    const unsigned short* wb = WhT + (size_t)gcol * HH + kq * 128 + q4 * 8;
    LDW(Bf[tile][0], wb, 0);
    LDW(Bf[tile][1], wb, 64);
    LDW(Bf[tile][2], wb, 128);
    LDW(Bf[tile][3], wb, 192);
  }
  asm volatile("s_waitcnt vmcnt(0)");

  const bool ld = (l15 < 4);       // only 16 lanes carry real A rows
  const int r4row = lane & 3;
  const int er = tid >> 5, ej = tid & 31;   // epilogue cell (tid<128)
  float c = 0.f;
  const unsigned long long M64 = 0xFFFF0000FFFF0000ULL;

  unsigned long long u0=0,u1=0,u2=0,u3=0,u4=0,u5=0,u6=0,u7=0,
                     u8=0,u9=0,u10=0,u11=0,u12=0,u13=0,u14=0,u15=0;

  // prime xw prefetch for t=0
  unsigned long long xq = 0;
  if (tid < 128) xq = xw[(((size_t)0 * 8 + cl) * 32 + jw) * 128 + tid];

  #pragma unroll 1
  for (int t = 0; t < TT; ++t) {
    const int par = t & 1;
    const unsigned int* hc = hbuf + (size_t)par * 32768 + cl * 4096;
    unsigned int* hn = hbuf + (size_t)(par ^ 1) * 32768 + cl * 4096;

    // ---- direct tagged poll: data arrives with the successful poll
    const unsigned long long pat =
        ((unsigned long long)(unsigned)t << 16) | ((unsigned long long)(unsigned)t << 48);
    if (ld) {
      const unsigned long long* hq =
          (const unsigned long long*)(hc + r4row * 1024 + kq * 128 + q4 * 8);
      int rc = 0;
      for (;;) {
        if (!(rc & 1)) {
          LDA0(u0,0);   LDA0(u1,8);   LDA0(u2,16);  LDA0(u3,24);
          LDA0(u4,128); LDA0(u5,136); LDA0(u6,144); LDA0(u7,152);
          LDA0(u8,256); LDA0(u9,264); LDA0(u10,272);LDA0(u11,280);
          LDA0(u12,384);LDA0(u13,392);LDA0(u14,400);LDA0(u15,408);
        } else {
          LDA1(u0,0);   LDA1(u1,8);   LDA1(u2,16);  LDA1(u3,24);
          LDA1(u4,128); LDA1(u5,136); LDA1(u6,144); LDA1(u7,152);
          LDA1(u8,256); LDA1(u9,264); LDA1(u10,272);LDA1(u11,280);
          LDA1(u12,384);LDA1(u13,392);LDA1(u14,400);LDA1(u15,408);
        }
        asm volatile("s_waitcnt vmcnt(0)");
        __builtin_amdgcn_sched_barrier(0);
        unsigned long long bad =
            ((u0 & M64) ^ pat)  | ((u1 & M64) ^ pat)  | ((u2 & M64) ^ pat)  | ((u3 & M64) ^ pat)  |
            ((u4 & M64) ^ pat)  | ((u5 & M64) ^ pat)  | ((u6 & M64) ^ pat)  | ((u7 & M64) ^ pat)  |
            ((u8 & M64) ^ pat)  | ((u9 & M64) ^ pat)  | ((u10 & M64) ^ pat) | ((u11 & M64) ^ pat) |
            ((u12 & M64) ^ pat) | ((u13 & M64) ^ pat) | ((u14 & M64) ^ pat) | ((u15 & M64) ^ pat);
        if (!__any(bad != 0)) break;
        __builtin_amdgcn_s_sleep(1);
        ++rc;
      }
    }

    // ---- prefetch NEXT step's xw under the MFMA phase
    unsigned long long xq_n = 0;
    if (tid < 128) {
      int tp = (t + 1 < TT) ? t + 1 : 0;
      xq_n = xw[(((size_t)tp * 8 + cl) * 32 + jw) * 128 + tid];
    }

    // ---- unpack tags out (v_perm) and MFMA: 8 tiles x 4 k-steps
    f32x4 acc[8] = {};
    {
      uint32x4 wv;
      #define KSTEP(ks, a0, a1, a2, a3)                                              \
        wv[0] = __builtin_amdgcn_perm((unsigned)((a0) >> 32), (unsigned)(a0), 0x05040100u); \
        wv[1] = __builtin_amdgcn_perm((unsigned)((a1) >> 32), (unsigned)(a1), 0x05040100u); \
        wv[2] = __builtin_amdgcn_perm((unsigned)((a2) >> 32), (unsigned)(a2), 0x05040100u); \
        wv[3] = __builtin_amdgcn_perm((unsigned)((a3) >> 32), (unsigned)(a3), 0x05040100u); \
        { bf16x8 av = __builtin_bit_cast(bf16x8, wv);                                \
          _Pragma("unroll")                                                          \
          for (int tile = 0; tile < 8; ++tile)                                       \
            acc[tile] = __builtin_amdgcn_mfma_f32_16x16x32_bf16(av, Bf[tile][ks], acc[tile], 0, 0, 0); }
      KSTEP(0, u0, u1, u2, u3)
      KSTEP(1, u4, u5, u6, u7)
      KSTEP(2, u8, u9, u10, u11)
      KSTEP(3, u12, u13, u14, u15)
      #undef KSTEP
    }

    if (q4 == 0) {
      #pragma unroll
      for (int tile = 0; tile < 8; ++tile)
        #pragma unroll
        for (int rg = 0; rg < 4; ++rg)
          red[par][kq][rg][tile * 16 + l15] = acc[tile][rg];
    }
    __syncthreads();

    // ---- epilogue: thread (er, ej) owns sample er, h-col j0+ej
    if (tid < 128) {
      float s0 = 0.f, s1 = 0.f, s2 = 0.f, s3 = 0.f;
      #pragma unroll
      for (int k2 = 0; k2 < 8; ++k2) {
        s0 += red[par][k2][er][ej];
        s1 += red[par][k2][er][32 + ej];
        s2 += red[par][k2][er][64 + ej];
        s3 += red[par][k2][er][96 + ej];
      }
      float ai  = s0 + bf2f((unsigned short)xq);
      float af_ = s1 + bf2f((unsigned short)(xq >> 16));
      float ao  = s2 + bf2f((unsigned short)(xq >> 32));
      float ag  = s3 + bf2f((unsigned short)(xq >> 48));
      float ig = sigm(ai), fg = sigm(af_), og = sigm(ao);
      float gg = tanh_f(ag);
      c = fg * c + ig * gg;
      float hv = og * tanh_f(c);

      unsigned int hp = (unsigned int)f2bf(hv) | ((unsigned int)(t + 1) << 16);
      __hip_atomic_store(hn + er * 1024 + j0 + ej, hp,
                         __ATOMIC_RELAXED, __HIP_MEMORY_SCOPE_AGENT);
      out[((size_t)(cl * 4 + er) * TT + t) * HH + j0 + ej] = hv;
    }
    xq = xq_n;
  }
}

extern "C" void kernel_launch(void* const* d_in, const int* in_sizes, int n_in,
                              void* d_out, int out_size, void* d_ws, size_t ws_size,
                              hipStream_t stream) {
  (void)in_sizes; (void)n_in; (void)out_size;
  const float* x  = (const float*)d_in[0];
  const float* h0 = (const float*)d_in[1];
  const float* Wx = (const float*)d_in[2];
  const float* Wh = (const float*)d_in[3];
  const float* b  = (const float*)d_in[4];
  float* out = (float*)d_out;

  char* ws = (char*)d_ws;
  size_t o_xw  = 0;
  size_t o_xbf = o_xw  + (size_t)32768 * 4096 * 2;  // xw   : 268435456 B
  size_t o_wxT = o_xbf + (size_t)32768 * 1024 * 2;  // xbf  :  67108864 B
  size_t o_whT = o_wxT + (size_t)4096 * 1024 * 2;   // WxT  :   8388608 B
  size_t o_hb  = o_whT + (size_t)4096 * 1024 * 2;   // WhT  :   8388608 B
  size_t need  = o_hb  + (size_t)2 * 32768 * 4;     // hbuf :    262144 B
  if (ws_size < need) {
    fprintf(stderr, "kernel_launch: ws_size %zu < needed %zu\n", ws_size, need);
    return;
  }
  unsigned short* xw  = (unsigned short*)(ws + o_xw);
  unsigned short* xbf = (unsigned short*)(ws + o_xbf);
  unsigned short* wxT = (unsigned short*)(ws + o_wxT);
  unsigned short* whT = (unsigned short*)(ws + o_whT);
  unsigned int*   hb  = (unsigned int*)(ws + o_hb);

  // kill stale tags from previous graph replay, then write h0 with tag 0
  hipMemsetAsync(hb, 0xFF, (size_t)2 * 32768 * 4, stream);
  pack_h0<<<128, 256, 0, stream>>>(h0, hb);
  cast_bf4<<<32768, 256, 0, stream>>>((const float4*)x, (uint2*)xbf, 33554432 / 4);
  transp_cast<<<1024, 256, 0, stream>>>(Wx, wxT, 1024, 4096);
  transp_cast<<<1024, 256, 0, stream>>>(Wh, whT, 1024, 4096);
  gemm_xw<<<8192, 256, 0, stream>>>(xbf, wxT, b, xw);

  void* args[] = { (void*)&xw, (void*)&whT, (void*)&hb, (void*)&out };
  hipLaunchCooperativeKernel(lstm_rec, dim3(256), dim3(512), args, 0, stream);
}